// Round 8
// baseline (155.108 us; speedup 1.0000x reference)
//
#include <hip/hip_runtime.h>

#define B_ 4
#define N_ 1024
#define E_ 512
#define H_ 8
#define D_ 64
#define BH_ 32
#define KVB 32

typedef __bf16 bf16;
typedef __bf16 bf16x8 __attribute__((ext_vector_type(8)));
typedef __bf16 bf16x4 __attribute__((ext_vector_type(4)));
typedef float f32x4 __attribute__((ext_vector_type(4)));

#define MFMA16 __builtin_amdgcn_mfma_f32_16x16x32_bf16

typedef const __attribute__((address_space(1))) void* gas_t;
typedef __attribute__((address_space(3))) void* las_t;

__device__ __forceinline__ void gload16(const void* g, void* l) {
    __builtin_amdgcn_global_load_lds((gas_t)g, (las_t)l, 16, 0, 0);
}

// ---------- prep: all fp32 -> bf16 hi/lo conversions in one launch ----------
__global__ __launch_bounds__(256) void prep_all(
    const float* __restrict__ X, const float* __restrict__ Wq,
    const float* __restrict__ Wk, const float* __restrict__ Wv,
    const float* __restrict__ Wo,
    bf16* __restrict__ Xh, bf16* __restrict__ Xl,
    bf16* __restrict__ Wqh, bf16* __restrict__ Wql,
    bf16* __restrict__ Wkh, bf16* __restrict__ Wkl,
    bf16* __restrict__ Wvh,
    bf16* __restrict__ Woh, bf16* __restrict__ Wol)
{
    const int NX = B_ * N_ * E_;
    const int NW = E_ * E_;
    int i = blockIdx.x * 256 + threadIdx.x;
    if (i < NX) {
        float x = X[i]; bf16 h = (bf16)x;
        Xh[i] = h; Xl[i] = (bf16)(x - (float)h);
        return;
    }
    i -= NX;
    int w = i >> 18, j = i & (NW - 1);
    if (w == 0) { float x = Wq[j]; bf16 h = (bf16)x; Wqh[j] = h; Wql[j] = (bf16)(x - (float)h); }
    else if (w == 1) { float x = Wk[j]; bf16 h = (bf16)x; Wkh[j] = h; Wkl[j] = (bf16)(x - (float)h); }
    else if (w == 2) { float x = Wv[j]; Wvh[j] = (bf16)x; }
    else if (w == 3) { float x = Wo[j]; bf16 h = (bf16)x; Woh[j] = h; Wol[j] = (bf16)(x - (float)h); }
}

// ---------- fused QKV projection with W-tile LDS staging ----------
__global__ __launch_bounds__(256) void qkv_gemm(
    const bf16* __restrict__ Xh, const bf16* __restrict__ Xl,
    const bf16* __restrict__ Wqh, const bf16* __restrict__ Wql, const float* __restrict__ bq,
    const bf16* __restrict__ Wkh, const bf16* __restrict__ Wkl, const float* __restrict__ bk,
    const bf16* __restrict__ Wvh, const float* __restrict__ bvv,
    bf16* __restrict__ Qh, bf16* __restrict__ Ql,
    bf16* __restrict__ Kh, bf16* __restrict__ Kl,
    bf16* __restrict__ Vt)
{
    __shared__ alignas(16) bf16 wlds[2][2][64 * 32];
    __shared__ alignas(16) bf16 tlds[64 * 72];
    const int z = blockIdx.z;
    const int e0 = blockIdx.x * 64;
    const int m0 = blockIdx.y * 64;
    const int tid = threadIdx.x;
    const int w = tid >> 6, l = tid & 63, lr = l & 15, lg = l >> 4;
    const int h = e0 >> 6;
    const bool three = (z != 2);

    const bf16* Wh = (z == 0) ? Wqh : ((z == 1) ? Wkh : Wvh);
    const bf16* Wl = (z == 0) ? Wql : ((z == 1) ? Wkl : Wqh /*unused*/);

    const int wrow = 16 * w + (l >> 2);
    const int wcol = 8 * ((l & 3) ^ ((l >> 3) & 3));
    const bf16* whsrc = Wh + (size_t)(e0 + wrow) * E_ + wcol;
    const bf16* wlsrc = Wl + (size_t)(e0 + wrow) * E_ + wcol;

#define WSTAGE(k0, bi) do {                                  \
        gload16(whsrc + (k0), &wlds[bi][0][w * 512]);        \
        if (three) gload16(wlsrc + (k0), &wlds[bi][1][w * 512]); \
    } while (0)

    WSTAGE(0, 0);

    f32x4 acc[4] = {};
    const bf16* xh = &Xh[(size_t)(m0 + w * 16 + lr) * E_];
    const bf16* xl = &Xl[(size_t)(m0 + w * 16 + lr) * E_];

    for (int it = 0; it < 16; ++it) {
        const int k0 = it * 32;
        const int bi = it & 1;
        if (it < 15) {
            WSTAGE(k0 + 32, bi ^ 1);
            __builtin_amdgcn_sched_barrier(0);
            if (three) asm volatile("s_waitcnt vmcnt(2)" ::: "memory");
            else       asm volatile("s_waitcnt vmcnt(1)" ::: "memory");
        } else {
            asm volatile("s_waitcnt vmcnt(0)" ::: "memory");
        }
        __builtin_amdgcn_sched_barrier(0);
        __builtin_amdgcn_s_barrier();

        bf16x8 ah = *(const bf16x8*)(xh + k0 + lg * 8);
        bf16x8 al = three ? *(const bf16x8*)(xl + k0 + lg * 8) : ah;

        const char* whb = (const char*)&wlds[bi][0][0];
        const char* wlb = (const char*)&wlds[bi][1][0];
        const int wsw = ((lr >> 1) & 3) << 4;
#pragma unroll
        for (int t = 0; t < 4; ++t) {
            int rb = (16 * t + lr) * 64;
            bf16x8 bh = *(const bf16x8*)(whb + rb + ((lg * 16) ^ wsw));
            acc[t] = MFMA16(ah, bh, acc[t], 0, 0, 0);
            if (three) {
                bf16x8 bl = *(const bf16x8*)(wlb + rb + ((lg * 16) ^ wsw));
                acc[t] = MFMA16(al, bh, acc[t], 0, 0, 0);
                acc[t] = MFMA16(ah, bl, acc[t], 0, 0, 0);
            }
        }
        __builtin_amdgcn_s_barrier();
    }
#undef WSTAGE

    if (z == 2) {
        const float* bias = bvv;
#pragma unroll
        for (int t = 0; t < 4; ++t) {
            float bv = bias[e0 + 16 * t + lr];
#pragma unroll
            for (int r = 0; r < 4; ++r)
                tlds[(16 * t + lr) * 72 + w * 16 + lg * 4 + r] = (bf16)(acc[t][r] + bv);
        }
        __syncthreads();
        int d = tid >> 2, c0 = (tid & 3) * 16;
        int b = m0 >> 10, n = (m0 & (N_ - 1)) + c0;
        bf16x8* dst = (bf16x8*)&Vt[((size_t)(b * H_ + h) * D_ + d) * N_ + n];
        const bf16x8* s = (const bf16x8*)&tlds[d * 72 + c0];
        dst[0] = s[0];
        dst[1] = s[1];
        return;
    }

    const float* bias = z ? bk : bq;
    bf16* Oh = z ? Kh : Qh;
    bf16* Ol = z ? Kl : Ql;
#pragma unroll
    for (int t = 0; t < 4; ++t) {
        float bv = bias[e0 + 16 * t + lr];
#pragma unroll
        for (int r = 0; r < 4; ++r) {
            int m = m0 + w * 16 + lg * 4 + r;
            int b = m >> 10, n = m & (N_ - 1);
            float v = acc[t][r] + bv;
            bf16 hi = (bf16)v;
            size_t idx = ((size_t)(b * H_ + h) * N_ + n) * D_ + 16 * t + lr;
            Oh[idx] = hi;
            Ol[idx] = (bf16)(v - (float)hi);
        }
    }
}

// ---------- fused attention: swapped S^T; masks in REGISTERS (per-lane f32x4),
// K via gload_lds double-buffer, V direct. LDS 21.5 KB -> high occupancy. ----------
__global__ __launch_bounds__(256, 3) void attn_kernel(
    const bf16* __restrict__ Qh_, const bf16* __restrict__ Ql_,
    const bf16* __restrict__ Kh_, const bf16* __restrict__ Kl_,
    const bf16* __restrict__ Vt_,
    const float* __restrict__ rn,
    const float* __restrict__ addm, const float* __restrict__ multm,
    float* __restrict__ Opart, float* __restrict__ Mb, float* __restrict__ Lb,
    int ch)
{
    __shared__ alignas(16) bf16 khlds[2][32 * 64];   // 8 KB
    __shared__ alignas(16) bf16 kllds[2][32 * 64];   // 8 KB
    __shared__ alignas(16) bf16 plds[4][16 * 40];    // 5 KB  -> 21.5 KB total

    const int by = blockIdx.y;
    const int bh = by & (BH_ - 1), c = by >> 5;
    const int b = bh >> 3;
    const int kvb = c * ch;
    const int tid = threadIdx.x;
    const int w = tid >> 6, l = tid & 63, lr = l & 15, lg = l >> 4;
    const int q0 = blockIdx.x * 64 + w * 16;
    bf16* pw = &plds[w][0];

    const bf16* qb = &Qh_[((size_t)bh * N_ + q0 + lr) * D_];
    const bf16* qlb = &Ql_[((size_t)bh * N_ + q0 + lr) * D_];
    bf16x8 qh0 = *(const bf16x8*)(qb + lg * 8);
    bf16x8 qh1 = *(const bf16x8*)(qb + 32 + lg * 8);
    bf16x8 ql0 = *(const bf16x8*)(qlb + lg * 8);
    bf16x8 ql1 = *(const bf16x8*)(qlb + 32 + lg * 8);

    const float rnq = rn[b * N_ + q0 + lr] * 0.125f;

    float mrun = -3e38f, lrun = 0.f;
    f32x4 acc[4] = {};

    // per-lane mask bases: row q0+lr, cols 16t + 4lg (f32x4)
    const size_t mb0 = (size_t)bh * N_ * N_;
    const float* abase = addm + mb0 + (size_t)(q0 + lr) * N_ + 4 * lg;
    const float* mbase = multm + mb0 + (size_t)(q0 + lr) * N_ + 4 * lg;
    // K staging source (pre-swizzled rows for linear gload_lds dest)
    const int krow = 8 * w + (l >> 3), kcol = 8 * ((l & 7) ^ ((l >> 3) & 7));
    const bf16* khsrc = Kh_ + ((size_t)bh * N_ + krow) * D_ + kcol;
    const bf16* klsrc = Kl_ + ((size_t)bh * N_ + krow) * D_ + kcol;
    // V direct base
    const bf16* vbase = Vt_ + ((size_t)bh * D_ + lr) * N_ + 8 * lg;

#define KSTAGE(kv, bi) do {                                         \
        gload16(khsrc + (size_t)(kv) * D_, &khlds[bi][w * 512]);    \
        gload16(klsrc + (size_t)(kv) * D_, &kllds[bi][w * 512]);    \
    } while (0)

    // prologue: tile-0 masks into regs, tile-0 K into LDS
    f32x4 maC[2], mmC[2], maN[2], mmN[2];
    maC[0] = *(const f32x4*)(abase + kvb);
    maC[1] = *(const f32x4*)(abase + kvb + 16);
    mmC[0] = *(const f32x4*)(mbase + kvb);
    mmC[1] = *(const f32x4*)(mbase + kvb + 16);
    KSTAGE(kvb, 0);

    const int nt = ch / KVB;
    for (int tile = 0; tile < nt; ++tile) {
        const int kv0 = kvb + tile * KVB;
        const int bi = tile & 1;
        const bool more = (tile + 1 < nt);

        // 1) next-tile mask loads (oldest of this iter; compiler-managed waits)
        if (more) {
            const int kvn = kv0 + KVB;
            maN[0] = *(const f32x4*)(abase + kvn);
            maN[1] = *(const f32x4*)(abase + kvn + 16);
            mmN[0] = *(const f32x4*)(mbase + kvn);
            mmN[1] = *(const f32x4*)(mbase + kvn + 16);
        }
        __builtin_amdgcn_sched_barrier(0);

        // 2) V(t) loads
        bf16x8 vv[4];
#pragma unroll
        for (int t = 0; t < 4; ++t)
            vv[t] = *(const bf16x8*)(vbase + (size_t)(16 * t) * N_ + kv0);
        __builtin_amdgcn_sched_barrier(0);

        // 3) next-tile K stage (youngest), then wait for K-stage(t) only
        if (more) {
            KSTAGE(kv0 + KVB, bi ^ 1);
            __builtin_amdgcn_sched_barrier(0);
            asm volatile("s_waitcnt vmcnt(10)" ::: "memory");  // maN4+V4+KSTAGE2 in flight
        } else {
            asm volatile("s_waitcnt vmcnt(4)" ::: "memory");   // V4 in flight
        }
        __builtin_amdgcn_sched_barrier(0);
        __builtin_amdgcn_s_barrier();

        // ---- K fragments from LDS (swizzled reads) ----
        const char* khb = (const char*)&khlds[bi][0];
        const char* klb = (const char*)&kllds[bi][0];
        const int ksw = (lr & 7) << 4;
        bf16x8 kh[2][2], kl[2][2];
#pragma unroll
        for (int t = 0; t < 2; ++t) {
            int rb = (16 * t + lr) * 128;
            kh[t][0] = *(const bf16x8*)(khb + rb + ((lg * 16) ^ ksw));
            kh[t][1] = *(const bf16x8*)(khb + rb + ((64 + lg * 16) ^ ksw));
            kl[t][0] = *(const bf16x8*)(klb + rb + ((lg * 16) ^ ksw));
            kl[t][1] = *(const bf16x8*)(klb + rb + ((64 + lg * 16) ^ ksw));
        }

        // ---- S^T = K Q^T (hi/lo split) ----
        f32x4 z[2];
#pragma unroll
        for (int t = 0; t < 2; ++t) {
            f32x4 zz = {};
            zz = MFMA16(kh[t][0], qh0, zz, 0, 0, 0);
            zz = MFMA16(kh[t][1], qh1, zz, 0, 0, 0);
            zz = MFMA16(kh[t][0], ql0, zz, 0, 0, 0);
            zz = MFMA16(kh[t][1], ql1, zz, 0, 0, 0);
            zz = MFMA16(kl[t][0], qh0, zz, 0, 0, 0);
            zz = MFMA16(kl[t][1], qh1, zz, 0, 0, 0);
            z[t] = zz;
        }

        // ---- scale + add (masks already in registers) ----
        float sv[2][4];
#pragma unroll
        for (int t = 0; t < 2; ++t)
#pragma unroll
            for (int r = 0; r < 4; ++r)
                sv[t][r] = z[t][r] * rnq + maC[t][r];

        // ---- per-lane online softmax ----
        float vmax = sv[0][0];
#pragma unroll
        for (int t = 0; t < 2; ++t)
#pragma unroll
            for (int r = 0; r < 4; ++r) vmax = fmaxf(vmax, sv[t][r]);
        vmax = fmaxf(vmax, __shfl_xor(vmax, 16));
        vmax = fmaxf(vmax, __shfl_xor(vmax, 32));
        float mn = fmaxf(mrun, vmax);
        float rs = __expf(mrun - mn);
        mrun = mn;
        lrun *= rs;
#pragma unroll
        for (int t = 0; t < 4; ++t) acc[t] *= rs;
        float pe[2][4];
        float rsum = 0.f;
#pragma unroll
        for (int t = 0; t < 2; ++t)
#pragma unroll
            for (int r = 0; r < 4; ++r) { pe[t][r] = __expf(sv[t][r] - mn); rsum += pe[t][r]; }
        rsum += __shfl_xor(rsum, 16);
        rsum += __shfl_xor(rsum, 32);
        lrun += rsum;

        // ---- P_eff -> plds[q=lr][k] ----
#pragma unroll
        for (int t = 0; t < 2; ++t) {
            bf16x4 pk;
#pragma unroll
            for (int r = 0; r < 4; ++r) pk[r] = (bf16)(pe[t][r] * mmC[t][r]);
            *(bf16x4*)(pw + lr * 40 + 16 * t + 4 * lg) = pk;
        }

        // ---- PV (compiler inserts precise wait for vv) ----
        bf16x8 pa = *(const bf16x8*)(pw + lr * 40 + 8 * lg);
#pragma unroll
        for (int t = 0; t < 4; ++t)
            acc[t] = MFMA16(vv[t], pa, acc[t], 0, 0, 0);

        __builtin_amdgcn_s_barrier();

        // ---- rotate mask buffers ----
        if (more) {
#pragma unroll
            for (int t = 0; t < 2; ++t) {
                maC[t] = maN[t];
                mmC[t] = mmN[t];
            }
        }
    }

    // ---- store unnormalized partials (vectorized) ----
    const size_t cb = ((size_t)c * BH_ + bh) * N_;
    float* ob = &Opart[(cb + q0 + lr) * D_];
#pragma unroll
    for (int t = 0; t < 4; ++t)
        *(f32x4*)(ob + 16 * t + 4 * lg) = acc[t];
    if (lg == 0) {
        Mb[cb + q0 + lr] = mrun;
        Lb[cb + q0 + lr] = lrun;
    }
#undef KSTAGE
}

// ---------- merge KV-split partials -> normalized attention out (hi/lo bf16) ----------
__global__ __launch_bounds__(256) void merge_kernel(
    const float* __restrict__ Opart, const float* __restrict__ Mb,
    const float* __restrict__ Lb,
    bf16* __restrict__ AOh, bf16* __restrict__ AOl, int ks)
{
    int idx = blockIdx.x * 256 + threadIdx.x;
    int bh = idx >> 14;
    int rem = idx & 16383;
    int q = rem >> 4, d4 = rem & 15;

    float M = -3e38f;
    for (int c = 0; c < ks; ++c)
        M = fmaxf(M, Mb[((size_t)c * BH_ + bh) * N_ + q]);
    float L = 0.f;
    f32x4 o = {};
    for (int c = 0; c < ks; ++c) {
        size_t base = ((size_t)c * BH_ + bh) * N_ + q;
        float wgt = __expf(Mb[base] - M);
        L += wgt * Lb[base];
        f32x4 v = *(const f32x4*)&Opart[base * D_ + d4 * 4];
        o += wgt * v;
    }
    float inv = 1.f / L;
    int b = bh >> 3, h = bh & 7;
    size_t ob = ((size_t)b * N_ + q) * E_ + h * D_ + d4 * 4;
    bf16x4 hi, lo;
#pragma unroll
    for (int j = 0; j < 4; ++j) {
        float x = o[j] * inv;
        bf16 hh = (bf16)x;
        hi[j] = hh;
        lo[j] = (bf16)(x - (float)hh);
    }
    *(bf16x4*)&AOh[ob] = hi;
    *(bf16x4*)&AOl[ob] = lo;
}

// ---------- output projection with W-tile LDS staging, fp32 out + bias ----------
__global__ __launch_bounds__(256) void out_gemm(
    const bf16* __restrict__ Ah, const bf16* __restrict__ Al,
    const bf16* __restrict__ Wh, const bf16* __restrict__ Wl,
    const float* __restrict__ bias,
    float* __restrict__ out)
{
    __shared__ alignas(16) bf16 wlds[2][2][64 * 32];
    const int e0 = blockIdx.x * 64;
    const int m0 = blockIdx.y * 64;
    const int tid = threadIdx.x;
    const int w = tid >> 6, l = tid & 63, lr = l & 15, lg = l >> 4;

    const int wrow = 16 * w + (l >> 2);
    const int wcol = 8 * ((l & 3) ^ ((l >> 3) & 3));
    const bf16* whsrc = Wh + (size_t)(e0 + wrow) * E_ + wcol;
    const bf16* wlsrc = Wl + (size_t)(e0 + wrow) * E_ + wcol;

#define WSTAGE(k0, bi) do {                               \
        gload16(whsrc + (k0), &wlds[bi][0][w * 512]);     \
        gload16(wlsrc + (k0), &wlds[bi][1][w * 512]);     \
    } while (0)

    WSTAGE(0, 0);

    f32x4 acc[4] = {};
    const bf16* ah_p = &Ah[(size_t)(m0 + w * 16 + lr) * E_];
    const bf16* al_p = &Al[(size_t)(m0 + w * 16 + lr) * E_];

    for (int it = 0; it < 16; ++it) {
        const int k0 = it * 32;
        const int bi = it & 1;
        if (it < 15) {
            WSTAGE(k0 + 32, bi ^ 1);
            __builtin_amdgcn_sched_barrier(0);
            asm volatile("s_waitcnt vmcnt(2)" ::: "memory");
        } else {
            asm volatile("s_waitcnt vmcnt(0)" ::: "memory");
        }
        __builtin_amdgcn_sched_barrier(0);
        __builtin_amdgcn_s_barrier();

        bf16x8 ah = *(const bf16x8*)(ah_p + k0 + lg * 8);
        bf16x8 al = *(const bf16x8*)(al_p + k0 + lg * 8);
        const char* whb = (const char*)&wlds[bi][0][0];
        const char* wlb = (const char*)&wlds[bi][1][0];
        const int wsw = ((lr >> 1) & 3) << 4;
#pragma unroll
        for (int t = 0; t < 4; ++t) {
            int rb = (16 * t + lr) * 64;
            bf16x8 bh = *(const bf16x8*)(whb + rb + ((lg * 16) ^ wsw));
            bf16x8 bl = *(const bf16x8*)(wlb + rb + ((lg * 16) ^ wsw));
            acc[t] = MFMA16(ah, bh, acc[t], 0, 0, 0);
            acc[t] = MFMA16(al, bh, acc[t], 0, 0, 0);
            acc[t] = MFMA16(ah, bl, acc[t], 0, 0, 0);
        }
        __builtin_amdgcn_s_barrier();
    }
#undef WSTAGE

#pragma unroll
    for (int t = 0; t < 4; ++t) {
        float bv = bias[e0 + 16 * t + lr];
#pragma unroll
        for (int r = 0; r < 4; ++r) {
            int m = m0 + w * 16 + lg * 4 + r;
            out[(size_t)m * E_ + e0 + 16 * t + lr] = acc[t][r] + bv;
        }
    }
}

extern "C" void kernel_launch(void* const* d_in, const int* in_sizes, int n_in,
                              void* d_out, int out_size, void* d_ws, size_t ws_size,
                              hipStream_t stream) {
    const float* X = (const float*)d_in[0];
    const float* rn = (const float*)d_in[1];
    const float* addm = (const float*)d_in[2];
    const float* multm = (const float*)d_in[3];
    const float* Wq = (const float*)d_in[4];
    const float* bq = (const float*)d_in[5];
    const float* Wk = (const float*)d_in[6];
    const float* bk = (const float*)d_in[7];
    const float* Wv = (const float*)d_in[8];
    const float* bv = (const float*)d_in[9];
    const float* Wo = (const float*)d_in[10];
    const float* bo = (const float*)d_in[11];
    float* out = (float*)d_out;

    const size_t SZ_X = (size_t)B_ * N_ * E_;
    const size_t SZ_W = (size_t)E_ * E_;

    bf16* p = (bf16*)d_ws;
    bf16* Xh = p;  p += SZ_X;
    bf16* Xl = p;  p += SZ_X;
    bf16* Wqh = p; p += SZ_W;
    bf16* Wql = p; p += SZ_W;
    bf16* Wkh = p; p += SZ_W;
    bf16* Wkl = p; p += SZ_W;
    bf16* Wvh = p; p += SZ_W;
    bf16* Woh = p; p += SZ_W;
    bf16* Wol = p; p += SZ_W;
    bf16* Qh = p;  p += SZ_X;
    bf16* Ql = p;  p += SZ_X;
    bf16* Kh = p;  p += SZ_X;
    bf16* Kl = p;  p += SZ_X;
    bf16* Vt = p;  p += SZ_X;
    bf16* AOh = p; p += SZ_X;
    bf16* AOl = p; p += SZ_X;

    size_t fixed_bytes = (size_t)((char*)p - (char*)d_ws);
    size_t per_ks = (size_t)BH_ * N_ * D_ * 4 + (size_t)BH_ * N_ * 2 * 4;
    int ks = 4;
    if (fixed_bytes + 4 * per_ks > ws_size) ks = 2;
    if (fixed_bytes + 2 * per_ks > ws_size) ks = 1;

    float* Opart = (float*)p;
    float* Mb = Opart + (size_t)ks * BH_ * N_ * D_;
    float* Lb = Mb + (size_t)ks * BH_ * N_;

    const int NPREP = B_ * N_ * E_ + 4 * E_ * E_;
    prep_all<<<dim3(NPREP / 256), 256, 0, stream>>>(X, Wq, Wk, Wv, Wo,
        Xh, Xl, Wqh, Wql, Wkh, Wkl, Wvh, Woh, Wol);

    dim3 gq(E_ / 64, (B_ * N_) / 64, 3);
    qkv_gemm<<<gq, 256, 0, stream>>>(Xh, Xl, Wqh, Wql, bq, Wkh, Wkl, bk, Wvh, bv,
                                     Qh, Ql, Kh, Kl, Vt);

    attn_kernel<<<dim3(N_ / 64, ks * BH_), 256, 0, stream>>>(
        Qh, Ql, Kh, Kl, Vt, rn, addm, multm, Opart, Mb, Lb, N_ / ks);

    merge_kernel<<<dim3((BH_ * N_ * (D_ / 4)) / 256), 256, 0, stream>>>(
        Opart, Mb, Lb, AOh, AOl, ks);

    dim3 gg(E_ / 64, (B_ * N_) / 64);
    out_gemm<<<gg, 256, 0, stream>>>(AOh, AOl, Woh, Wol, bo, out);
}